// Round 16
// baseline (533.691 us; speedup 1.0000x reference)
//
#include <hip/hip_runtime.h>
#include <hip/hip_bf16.h>
#include <math.h>

// SharedLora on MI355X — round 16: ABLATION round.
// r15 confirmed the atomic convoy (459->196 us) but k_main=196 vs ~65 us
// roofline with ALL pipes idle; 3 different structures land 184-196. Per
// guide mistake #8: ablate before optimizing. k_main_t<MODE> (0=stage C+U,
// 1=+M1 syrk, 2=+M2 w-proj, 3=full/real) all launched; rocprof table gives
// per-variant dur directly. Phases byte-identical to r15.

#define NROI 256
#define NC 20
#define NFINAL 8000
#define NCUTS 500000
#define TB 256
#define NTILE 32
#define UTSTR 40
#define NKL (NROI * NTILE + NROI)   // 8448 KL partial slots

typedef __attribute__((ext_vector_type(8))) short bf16x8;
typedef __attribute__((ext_vector_type(4))) float f32x4;

static __device__ __forceinline__ ushort bfr(float x) {
    union { __hip_bfloat16 h; ushort u; } v;
    v.h = __float2bfloat16(x);
    return v.u;
}
static __device__ __forceinline__ bf16x8 pack8(float4 a, float4 b) {
    union { bf16x8 v; ushort s[8]; } u;
    u.s[0] = bfr(a.x); u.s[1] = bfr(a.y); u.s[2] = bfr(a.z); u.s[3] = bfr(a.w);
    u.s[4] = bfr(b.x); u.s[5] = bfr(b.y); u.s[6] = bfr(b.z); u.s[7] = bfr(b.w);
    return u.v;
}

__global__ void k_init(const float* __restrict__ comp,
                       float* __restrict__ g2, float* __restrict__ gfull,
                       ushort* __restrict__ compPad)
{
    const int tid = threadIdx.x;
    for (int i = tid; i < 400; i += 256) {
        const int a = i / 20, b = i % 20;
        float s = 0.f;
#pragma unroll
        for (int c = 0; c < 20; c++) s += comp[a * 20 + c] * comp[b * 20 + c];
        g2[i] = (b < a) ? 0.f : (b == a ? s : 2.f * s);
    }
    for (int i = tid; i < 1024; i += 256) {
        const int rr = i >> 5, cc = i & 31;
        float s = 0.f;
        if (rr < 20 && cc < 20) {
#pragma unroll
            for (int c = 0; c < 20; c++) s += comp[rr * 20 + c] * comp[cc * 20 + c];
        }
        gfull[i] = s;
        const float v = (rr < 20 && cc < 20) ? comp[cc * 20 + rr] : 0.f;
        compPad[i] = bfr(v);
    }
}

template <int MODE>
__global__ __launch_bounds__(256, 2) void k_main_t(
    const float* __restrict__ gfull, const ushort* __restrict__ compPad,
    const float* __restrict__ wb0, const float* __restrict__ wd0,
    const float* __restrict__ wb1, const float* __restrict__ wd1,
    const float* __restrict__ wb2, const float* __restrict__ wd2,
    const float* __restrict__ wb3, const float* __restrict__ wd3,
    const float* __restrict__ wb4, const float* __restrict__ wd4,
    const float* __restrict__ wb5, const float* __restrict__ wd5,
    const float* __restrict__ wb6, const float* __restrict__ wd6,
    const int* __restrict__ regions_oi,
    __hip_bfloat16* __restrict__ w2,
    float* __restrict__ s_part, float* __restrict__ klbuf,
    float* __restrict__ dumm)
{
    __shared__ ushort Utsh[TB * UTSTR];
    __shared__ float cs_sh[20 * 64];
    __shared__ float biasf[TB];
    __shared__ float sexp_sh[20];
    __shared__ float klp[4];

    const int tid = threadIdx.x;
    const int wv = tid >> 6, ln = tid & 63;
    const int l15 = ln & 15, lg = ln >> 4;
    const int r = blockIdx.x >> 5;
    const int tile = blockIdx.x & 31;
    const int base = tile << 8;
    const int r0 = regions_oi[r];

    const float* __restrict__ p6 = wd6 + (size_t)r0 * (20 * 8000);
    const float* __restrict__ p5 = wd5 + (size_t)r0 * (20 * 4000);
    const float* __restrict__ p4 = wd4 + (size_t)r0 * (20 * 2000);
    const float* __restrict__ p3 = wd3 + (size_t)r0 * (20 * 1000);
    const float* __restrict__ p2 = wd2 + (size_t)r0 * (20 * 400);
    const float* __restrict__ p1 = wd1 + (size_t)r0 * (20 * 200);
    const float* __restrict__ p0 = wd0 + (size_t)r0 * (20 * 40);
    const float* __restrict__ b6 = wb6 + (size_t)r0 * 8000;
    const float* __restrict__ b5 = wb5 + (size_t)r0 * 4000;
    const float* __restrict__ b4 = wb4 + (size_t)r0 * 2000;
    const float* __restrict__ b3 = wb3 + (size_t)r0 * 1000;
    const float* __restrict__ b2 = wb2 + (size_t)r0 * 400;
    const float* __restrict__ b1 = wb1 + (size_t)r0 * 200;
    const float* __restrict__ b0 = wb0 + (size_t)r0 * 40;

    if (tid < 20) sexp_sh[tid] = 0.f;

    // ---- C: coarse sums cs[a][quad] + bias per bin ----
#pragma unroll 1
    for (int it = 0; it < 5; it++) {
        const int u = it * 256 + tid;
        const int a = u >> 6, qd = u & 63;
        const int j = base + 4 * qd;
        float v = 0.f;
        if (j < NFINAL)
            v = p4[a * 2000 + (j >> 2)] + p3[a * 1000 + (j >> 3)]
              + p2[a * 400 + j / 20] + p1[a * 200 + j / 40]
              + p0[a * 40 + j / 200];
        cs_sh[a * 64 + qd] = v;
    }
    {
        const int j = base + tid;
        float v = 0.f;
        if (j < NFINAL)
            v = b6[j] + b5[j >> 1] + b4[j >> 2] + b3[j >> 3]
              + b2[j / 20] + b1[j / 40] + b0[j / 200];
        biasf[tid] = v;
    }
    __syncthreads();

    // ---- U: Utsh[bin][a] bf16 (pad 20..31 zero) ----
    {
        const int j = base + tid;
        const bool ok = j < NFINAL;
        const int qd = tid >> 2;
#pragma unroll 1
        for (int it = 0; it < 5; it++) {
            float u[4];
#pragma unroll
            for (int i = 0; i < 4; i++) {
                const int a = 4 * it + i;
                float x6 = 0.f, x5 = 0.f;
                if (ok) {
                    x6 = p6[(size_t)a * 8000 + j];
                    x5 = p5[a * 4000 + (j >> 1)];
                }
                u[i] = x6 + x5 + cs_sh[a * 64 + qd];
            }
            *(ushort4*)&Utsh[tid * UTSTR + 4 * it] =
                make_ushort4(bfr(u[0]), bfr(u[1]), bfr(u[2]), bfr(u[3]));
        }
        const ushort4 z4 = make_ushort4(0, 0, 0, 0);
        *(ushort4*)&Utsh[tid * UTSTR + 20] = z4;
        *(ushort4*)&Utsh[tid * UTSTR + 24] = z4;
        *(ushort4*)&Utsh[tid * UTSTR + 28] = z4;
    }
    __syncthreads();

    // ---- M1: KL syrk, fragments direct from global ----
    if (MODE & 1) {
        f32x4 s00 = {0.f, 0.f, 0.f, 0.f};
        f32x4 s10 = {0.f, 0.f, 0.f, 0.f};
        f32x4 s11 = {0.f, 0.f, 0.f, 0.f};
#pragma unroll 1
        for (int ch = wv; ch < 15; ch += 4) {
            const float* P; int K, col0;
            if (ch < 8)       { P = p6; K = 8000; col0 = base + ch * 32; }
            else if (ch < 12) { P = p5; K = 4000; col0 = (base >> 1) + (ch - 8) * 32; }
            else if (ch < 14) { P = p4; K = 2000; col0 = (base >> 2) + (ch - 12) * 32; }
            else              { P = p3; K = 1000; col0 = (base >> 3); }
            const int cb = col0 + lg * 8;
            bf16x8 flo = {0,0,0,0,0,0,0,0}, fhi = {0,0,0,0,0,0,0,0};
            if (cb < K) {
                const float4 xa = *(const float4*)(P + (size_t)l15 * K + cb);
                const float4 xb = *(const float4*)(P + (size_t)l15 * K + cb + 4);
                flo = pack8(xa, xb);
                if (l15 < 4) {
                    const float4 ya = *(const float4*)(P + (size_t)(16 + l15) * K + cb);
                    const float4 yb = *(const float4*)(P + (size_t)(16 + l15) * K + cb + 4);
                    fhi = pack8(ya, yb);
                }
            }
            s00 = __builtin_amdgcn_mfma_f32_16x16x32_bf16(flo, flo, s00, 0, 0, 0);
            s10 = __builtin_amdgcn_mfma_f32_16x16x32_bf16(fhi, flo, s10, 0, 0, 0);
            s11 = __builtin_amdgcn_mfma_f32_16x16x32_bf16(fhi, fhi, s11, 0, 0, 0);
        }
        float qp = 0.f;
#pragma unroll
        for (int reg = 0; reg < 4; reg++) {
            const int rlo = lg * 4 + reg, rhi = 16 + lg * 4 + reg;
            qp += gfull[rlo * 32 + l15] * s00[reg];
            qp += 2.f * gfull[rhi * 32 + l15] * s10[reg];
            qp += gfull[rhi * 32 + 16 + l15] * s11[reg];
        }
#pragma unroll
        for (int off = 32; off > 0; off >>= 1) qp += __shfl_down(qp, off, 64);
        if (ln == 0) klp[wv] = qp;
    }

    // ---- M2: w = bias + comp^T U via MFMA ----
    if (MODE & 2) {
        bf16x8 fA0 = *(const bf16x8*)&compPad[l15 * 32 + lg * 8];
        bf16x8 fA1 = *(const bf16x8*)&compPad[(16 + l15) * 32 + lg * 8];
        float sA[4] = {0.f, 0.f, 0.f, 0.f};
        float sB[4] = {0.f, 0.f, 0.f, 0.f};
#pragma unroll 1
        for (int t = 0; t < 4; t++) {
            const int nt = 4 * t + wv;
            bf16x8 fB = *(const bf16x8*)&Utsh[(nt * 16 + l15) * UTSTR + lg * 8];
            const f32x4 z = {0.f, 0.f, 0.f, 0.f};
            f32x4 c0 = __builtin_amdgcn_mfma_f32_16x16x32_bf16(fA0, fB, z, 0, 0, 0);
            f32x4 c1 = __builtin_amdgcn_mfma_f32_16x16x32_bf16(fA1, fB, z, 0, 0, 0);
            const int binl = nt * 16 + l15;
            const int bin = base + binl;
            const float bi = biasf[binl];
            if (bin < NFINAL) {
#pragma unroll
                for (int reg = 0; reg < 4; reg++) {
                    const int c = lg * 4 + reg;
                    const float w = bi + c0[reg];
                    w2[(size_t)(r * 20 + c) * 8000 + bin] = __float2bfloat16(w);
                    sA[reg] += __expf(w);
                }
                if (lg == 0) {
#pragma unroll
                    for (int reg = 0; reg < 4; reg++) {
                        const float w = bi + c1[reg];
                        w2[(size_t)(r * 20 + 16 + reg) * 8000 + bin] = __float2bfloat16(w);
                        sB[reg] += __expf(w);
                    }
                }
            }
        }
#pragma unroll
        for (int reg = 0; reg < 4; reg++) {
            float s = sA[reg];
            s += __shfl_xor(s, 1, 64); s += __shfl_xor(s, 2, 64);
            s += __shfl_xor(s, 4, 64); s += __shfl_xor(s, 8, 64);
            if (l15 == 0) atomicAdd(&sexp_sh[lg * 4 + reg], s);
            float sb = sB[reg];
            sb += __shfl_xor(sb, 1, 64); sb += __shfl_xor(sb, 2, 64);
            sb += __shfl_xor(sb, 4, 64); sb += __shfl_xor(sb, 8, 64);
            if (ln == 0) atomicAdd(&sexp_sh[16 + reg], sb);
        }
    }
    __syncthreads();
    if (MODE & 2) {
        if (tid < 20) s_part[((size_t)r * NTILE + tile) * 20 + tid] = sexp_sh[tid];
    }
    if (MODE & 1) {
        if (tid == 0) klbuf[blockIdx.x] = klp[0] + klp[1] + klp[2] + klp[3];
    }
    if (MODE == 0) {
        // DCE guard: make staged LDS observable
        if (tid == 0)
            dumm[blockIdx.x] = biasf[17] + cs_sh[100] + (float)Utsh[1234];
    }
}

__global__ __launch_bounds__(256, 2) void k_klc(
    const float* __restrict__ g2,
    const float* __restrict__ wd0, const float* __restrict__ wd1,
    const float* __restrict__ wd2,
    const int* __restrict__ regions_oi, float* __restrict__ klbuf)
{
    __shared__ float klp[4];
    const int tid = threadIdx.x;
    const int r0 = regions_oi[blockIdx.x];
    const float* __restrict__ p2 = wd2 + (size_t)r0 * (20 * 400);
    const float* __restrict__ p1 = wd1 + (size_t)r0 * (20 * 200);
    const float* __restrict__ p0 = wd0 + (size_t)r0 * (20 * 40);

    float q = 0.f;
#pragma unroll 1
    for (int it = 0; it < 3; it++) {
        const int u = it * 256 + tid;
        if (u >= 640) break;
        const float* P; int K, col;
        if (u < 400)      { P = p2; K = 400; col = u; }
        else if (u < 600) { P = p1; K = 200; col = u - 400; }
        else              { P = p0; K = 40;  col = u - 600; }
        float x[20];
#pragma unroll
        for (int a = 0; a < 20; a++) x[a] = P[a * K + col];
#pragma unroll
        for (int a = 0; a < 20; a++) {
            float t = g2[a * 21] * x[a];
#pragma unroll
            for (int b = a + 1; b < 20; b++) t += g2[a * 20 + b] * x[b];
            q += x[a] * t;
        }
    }
#pragma unroll
    for (int off = 32; off > 0; off >>= 1) q += __shfl_down(q, off, 64);
    if ((tid & 63) == 0) klp[tid >> 6] = q;
    __syncthreads();
    if (tid == 0)
        klbuf[NROI * NTILE + blockIdx.x] = klp[0] + klp[1] + klp[2] + klp[3];
}

__global__ void k_klred(const float* __restrict__ klbuf, float* __restrict__ kl)
{
    __shared__ float part[4];
    const int tid = threadIdx.x;
    float s = 0.f;
    for (int i = tid; i < NKL; i += 256) s += klbuf[i];
#pragma unroll
    for (int off = 32; off > 0; off >>= 1) s += __shfl_down(s, off, 64);
    if ((tid & 63) == 0) part[tid >> 6] = s;
    __syncthreads();
    if (tid == 0)
        kl[0] = (float)(-80076800.0 * 1.3244036413128371)
              + (part[0] + part[1] + part[2] + part[3]) * (-0.5f / 2.25f);
}

__global__ void k_sub(const float* __restrict__ s_part, float* __restrict__ sub)
{
    const int i = blockIdx.x * 256 + threadIdx.x;
    if (i >= NROI * NC) return;
    const int r = i / 20, c = i % 20;
    float s = 0.f;
#pragma unroll 1
    for (int t = 0; t < NTILE; t++) s += s_part[(size_t)(r * NTILE + t) * 20 + c];
    sub[i] = logf(s) + 3.2188758248682006f;
}

__global__ void k_gather(const int* __restrict__ lri, const int* __restrict__ lci,
                         const int* __restrict__ cli, const int* __restrict__ coords,
                         const __hip_bfloat16* __restrict__ w2,
                         const float* __restrict__ sub,
                         float* __restrict__ out)
{
    const int i = blockIdx.x * 256 + threadIdx.x;
    if (i >= NCUTS) return;
    const int r = lri[i];
    const int c = cli[lci[i]];
    int co = coords[i];
    co = co < 0 ? 0 : (co > 199999 ? 199999 : co);
    const int bin = co / 25;
    const int rc = r * 20 + c;
    out[i] = __bfloat162float(w2[(size_t)rc * 8000 + bin]) - sub[rc];
}

extern "C" void kernel_launch(void* const* d_in, const int* in_sizes, int n_in,
                              void* d_out, int out_size, void* d_ws, size_t ws_size,
                              hipStream_t stream)
{
    const float* comp = (const float*)d_in[0];
    const float* wb[7];
    const float* wd[7];
    if (in_sizes[2] == 400000) {
        for (int l = 0; l < 7; l++) { wb[l] = (const float*)d_in[1 + 2 * l]; wd[l] = (const float*)d_in[2 + 2 * l]; }
    } else {
        for (int l = 0; l < 7; l++) { wb[l] = (const float*)d_in[1 + l]; wd[l] = (const float*)d_in[8 + l]; }
    }
    const int* regions_oi = (const int*)d_in[15];
    const int* lri   = (const int*)d_in[16];
    const int* lci   = (const int*)d_in[17];
    const int* cli   = (const int*)d_in[18];
    const int* coords= (const int*)d_in[19];
    float* out = (float*)d_out;

    __hip_bfloat16* w2 = (__hip_bfloat16*)d_ws;                     // 81.92 MB
    float* s_part = (float*)(w2 + (size_t)NROI * NC * NFINAL);      // 8192*20
    float* sub    = s_part + (size_t)NROI * NTILE * 20;             // 5120
    float* g2buf  = sub + NROI * NC;                                // 400
    float* gfull  = g2buf + 400;                                    // 1024
    ushort* compPad = (ushort*)(gfull + 1024);                      // 1024 u16
    float* klbuf  = (float*)(compPad + 1024);                       // 8448
    float* dumm   = klbuf + NKL;                                    // 8192
    float* spd    = dumm + NROI * NTILE;                            // 8192*20 dummy
    float* kld    = spd + (size_t)NROI * NTILE * 20;                // 8192 dummy
    const size_t need = (size_t)NROI * NC * NFINAL * 2
                      + ((size_t)NROI * NTILE * 20 * 2 + NROI * NC + 400 + 1024
                         + 512 + NKL + NROI * NTILE * 2) * sizeof(float);
    if (ws_size < need) return;

    k_init<<<1, 256, 0, stream>>>(comp, g2buf, gfull, compPad);
    // real outputs
    k_main_t<3><<<NROI * NTILE, 256, 0, stream>>>(gfull, compPad,
        wb[0], wd[0], wb[1], wd[1], wb[2], wd[2], wb[3], wd[3],
        wb[4], wd[4], wb[5], wd[5], wb[6], wd[6],
        regions_oi, w2, s_part, klbuf, dumm);
    // ablation probes (dummy outputs; durations read from rocprof table)
    k_main_t<0><<<NROI * NTILE, 256, 0, stream>>>(gfull, compPad,
        wb[0], wd[0], wb[1], wd[1], wb[2], wd[2], wb[3], wd[3],
        wb[4], wd[4], wb[5], wd[5], wb[6], wd[6],
        regions_oi, w2, spd, kld, dumm);
    k_main_t<1><<<NROI * NTILE, 256, 0, stream>>>(gfull, compPad,
        wb[0], wd[0], wb[1], wd[1], wb[2], wd[2], wb[3], wd[3],
        wb[4], wd[4], wb[5], wd[5], wb[6], wd[6],
        regions_oi, w2, spd, kld, dumm);
    k_main_t<2><<<NROI * NTILE, 256, 0, stream>>>(gfull, compPad,
        wb[0], wd[0], wb[1], wd[1], wb[2], wd[2], wb[3], wd[3],
        wb[4], wd[4], wb[5], wd[5], wb[6], wd[6],
        regions_oi, w2, spd, kld, dumm);
    k_klc<<<NROI, 256, 0, stream>>>(g2buf, wd[0], wd[1], wd[2],
        regions_oi, klbuf);
    k_klred<<<1, 256, 0, stream>>>(klbuf, out + NCUTS);
    k_sub<<<(NROI * NC + 255) / 256, 256, 0, stream>>>(s_part, sub);
    k_gather<<<(NCUTS + 255) / 256, 256, 0, stream>>>(lri, lci, cli, coords,
        w2, sub, out);
}

// Round 17
// 259.859 us; speedup vs baseline: 2.0538x; 2.0538x over previous
//
#include <hip/hip_runtime.h>
#include <hip/hip_bf16.h>
#include <math.h>

// SharedLora on MI355X — round 17: MLP-maximized staging.
// r16 ablation: staging ~100us of k_main's 196 (phases ~additive). r15's
// staging did 72 scalar loads/thread in unroll-1 loops -> ~2-5 loads in
// flight -> latency-bound at 2 TB/s. r17: load phase = ~15 INDEPENDENT wide
// f4/f2 loads/thread (raw levels+biases -> LDS verbatim, 42.7KB), then pure
// LDS folds (cs into L4sh, bias into biasf, U into L6sh f32). M2 = r10's
// proven VALU projection (SGPR comp via readfirstlane). M1 syrk + klbuf =
// r15 (validated). No global atomics anywhere.

#define NROI 256
#define NC 20
#define NFINAL 8000
#define NCUTS 500000
#define TB 256
#define NTILE 32
#define NKL (NROI * NTILE + NROI)   // 8448 KL partial slots

// LDS float offsets
#define L6O 0        // [20][256]
#define L5O 5120     // [20][128]
#define L4O 7680     // [20][64]  -> cs after fold
#define L3O 8960     // [20][32]
#define L2O 9600     // [20][16]
#define L1O 9920     // [20][8]
#define L0O 10080    // [20][4]
#define B5O 10160    // [128]
#define B4O 10288    // [64]
#define B3O 10352    // [32]
#define B2O 10384    // [16]
#define B1O 10400    // [8]
#define B0O 10408    // [4]
#define BFO 10416    // [256] bias per bin
#define SHSZ 10672   // 42,688 B

typedef __attribute__((ext_vector_type(8))) short bf16x8;
typedef __attribute__((ext_vector_type(4))) float f32x4;

static __device__ __forceinline__ ushort bfr(float x) {
    union { __hip_bfloat16 h; ushort u; } v;
    v.h = __float2bfloat16(x);
    return v.u;
}
static __device__ __forceinline__ bf16x8 pack8(float4 a, float4 b) {
    union { bf16x8 v; ushort s[8]; } u;
    u.s[0] = bfr(a.x); u.s[1] = bfr(a.y); u.s[2] = bfr(a.z); u.s[3] = bfr(a.w);
    u.s[4] = bfr(b.x); u.s[5] = bfr(b.y); u.s[6] = bfr(b.z); u.s[7] = bfr(b.w);
    return u.v;
}

__global__ void k_init(const float* __restrict__ comp,
                       float* __restrict__ g2, float* __restrict__ gfull,
                       float* __restrict__ compT)
{
    const int tid = threadIdx.x;
    for (int i = tid; i < 400; i += 256) {
        const int a = i / 20, b = i % 20;
        float s = 0.f;
#pragma unroll
        for (int c = 0; c < 20; c++) s += comp[a * 20 + c] * comp[b * 20 + c];
        g2[i] = (b < a) ? 0.f : (b == a ? s : 2.f * s);   // triangular (k_klc)
        compT[i] = comp[b * 20 + a];                      // compT[c][a]
    }
    for (int i = tid; i < 1024; i += 256) {
        const int rr = i >> 5, cc = i & 31;
        float s = 0.f;
        if (rr < 20 && cc < 20) {
#pragma unroll
            for (int c = 0; c < 20; c++) s += comp[rr * 20 + c] * comp[cc * 20 + c];
        }
        gfull[i] = s;                                      // full Gram, 0-padded
    }
}

__global__ __launch_bounds__(256, 2) void k_main(
    const float* __restrict__ gfull, const float* __restrict__ compT,
    const float* __restrict__ wb0, const float* __restrict__ wd0,
    const float* __restrict__ wb1, const float* __restrict__ wd1,
    const float* __restrict__ wb2, const float* __restrict__ wd2,
    const float* __restrict__ wb3, const float* __restrict__ wd3,
    const float* __restrict__ wb4, const float* __restrict__ wd4,
    const float* __restrict__ wb5, const float* __restrict__ wd5,
    const float* __restrict__ wb6, const float* __restrict__ wd6,
    const int* __restrict__ regions_oi,
    __hip_bfloat16* __restrict__ w2,
    float* __restrict__ s_part, float* __restrict__ klbuf)
{
    __shared__ float sh[SHSZ];
    __shared__ float klp[4];

    const int tid = threadIdx.x;
    const int wv = tid >> 6, ln = tid & 63;
    const int l15 = ln & 15, lg = ln >> 4;
    const int r = blockIdx.x >> 5;
    const int tile = blockIdx.x & 31;
    const int base = tile << 8;
    const int r0 = regions_oi[r];

    const float* __restrict__ p6 = wd6 + (size_t)r0 * (20 * 8000);
    const float* __restrict__ p5 = wd5 + (size_t)r0 * (20 * 4000);
    const float* __restrict__ p4 = wd4 + (size_t)r0 * (20 * 2000);
    const float* __restrict__ p3 = wd3 + (size_t)r0 * (20 * 1000);
    const float* __restrict__ p2 = wd2 + (size_t)r0 * (20 * 400);
    const float* __restrict__ p1 = wd1 + (size_t)r0 * (20 * 200);
    const float* __restrict__ p0 = wd0 + (size_t)r0 * (20 * 40);
    const float* __restrict__ b6 = wb6 + (size_t)r0 * 8000;
    const float* __restrict__ b5 = wb5 + (size_t)r0 * 4000;
    const float* __restrict__ b4 = wb4 + (size_t)r0 * 2000;
    const float* __restrict__ b3 = wb3 + (size_t)r0 * 1000;
    const float* __restrict__ b2 = wb2 + (size_t)r0 * 400;
    const float* __restrict__ b1 = wb1 + (size_t)r0 * 200;
    const float* __restrict__ b0 = wb0 + (size_t)r0 * 40;

    const int c2b = (base / 20) & ~3;
    const int c1b = (base / 40) & ~1;
    const int c0b = (base / 200) & ~1;

    // ==== LOAD PHASE: all independent wide loads, no intervening barriers ====
#pragma unroll
    for (int k = 0; k < 5; k++) {              // L6: 1280 f4 units
        const int u = tid + 256 * k;
        const int a = u >> 6, q = u & 63;
        const int j = base + 4 * q;
        float4 v = make_float4(0.f, 0.f, 0.f, 0.f);
        if (j < NFINAL) v = *(const float4*)(p6 + (size_t)a * 8000 + j);
        *(float4*)&sh[L6O + a * 256 + 4 * q] = v;
    }
#pragma unroll
    for (int k = 0; k < 3; k++) {              // L5: 640 f4 units
        const int u = tid + 256 * k;
        if (u < 640) {
            const int a = u >> 5, q = u & 31;
            const int col = (base >> 1) + 4 * q;
            float4 v = make_float4(0.f, 0.f, 0.f, 0.f);
            if (col < 4000) v = *(const float4*)(p5 + a * 4000 + col);
            *(float4*)&sh[L5O + a * 128 + 4 * q] = v;
        }
    }
#pragma unroll
    for (int k = 0; k < 2; k++) {              // L4: 320 f4 units
        const int u = tid + 256 * k;
        if (u < 320) {
            const int a = u >> 4, q = u & 15;
            const int col = (base >> 2) + 4 * q;
            float4 v = make_float4(0.f, 0.f, 0.f, 0.f);
            if (col < 2000) v = *(const float4*)(p4 + a * 2000 + col);
            *(float4*)&sh[L4O + a * 64 + 4 * q] = v;
        }
    }
    if (tid < 160) {                           // L3
        const int a = tid >> 3, q = tid & 7;
        const int col = (base >> 3) + 4 * q;
        float4 v = make_float4(0.f, 0.f, 0.f, 0.f);
        if (col < 1000) v = *(const float4*)(p3 + a * 1000 + col);
        *(float4*)&sh[L3O + a * 32 + 4 * q] = v;
    }
    if (tid < 80) {                            // L2 (16 cols, c2b-aligned)
        const int a = tid >> 2, q = tid & 3;
        const int col = c2b + 4 * q;
        float4 v = make_float4(0.f, 0.f, 0.f, 0.f);
        if (col < 400) v = *(const float4*)(p2 + a * 400 + col);
        *(float4*)&sh[L2O + a * 16 + 4 * q] = v;
    }
    if (tid < 80) {                            // L1 (8 cols, f2)
        const int a = tid >> 2, q = tid & 3;
        const int col = c1b + 2 * q;
        float2 v = make_float2(0.f, 0.f);
        if (col < 200) v = *(const float2*)(p1 + a * 200 + col);
        *(float2*)&sh[L1O + a * 8 + 2 * q] = v;
    }
    if (tid < 40) {                            // L0 (4 cols, f2)
        const int a = tid >> 1, q = tid & 1;
        const int col = c0b + 2 * q;
        float2 v = make_float2(0.f, 0.f);
        if (col < 40) v = *(const float2*)(p0 + a * 40 + col);
        *(float2*)&sh[L0O + a * 4 + 2 * q] = v;
    }
    if (tid < 64) {                            // b6 -> biasf
        const int j = base + 4 * tid;
        float4 v = make_float4(0.f, 0.f, 0.f, 0.f);
        if (j < NFINAL) v = *(const float4*)(b6 + j);
        *(float4*)&sh[BFO + 4 * tid] = v;
    }
    if (tid < 32) {                            // b5
        const int col = (base >> 1) + 4 * tid;
        float4 v = make_float4(0.f, 0.f, 0.f, 0.f);
        if (col < 4000) v = *(const float4*)(b5 + col);
        *(float4*)&sh[B5O + 4 * tid] = v;
    }
    if (tid < 16) {                            // b4
        const int col = (base >> 2) + 4 * tid;
        float4 v = make_float4(0.f, 0.f, 0.f, 0.f);
        if (col < 2000) v = *(const float4*)(b4 + col);
        *(float4*)&sh[B4O + 4 * tid] = v;
    }
    if (tid < 8) {                             // b3
        const int col = (base >> 3) + 4 * tid;
        float4 v = make_float4(0.f, 0.f, 0.f, 0.f);
        if (col < 1000) v = *(const float4*)(b3 + col);
        *(float4*)&sh[B3O + 4 * tid] = v;
    }
    if (tid < 4) {                             // b2
        const int col = c2b + 4 * tid;
        float4 v = make_float4(0.f, 0.f, 0.f, 0.f);
        if (col < 400) v = *(const float4*)(b2 + col);
        *(float4*)&sh[B2O + 4 * tid] = v;
    }
    if (tid < 4) {                             // b1 (f2)
        const int col = c1b + 2 * tid;
        float2 v = make_float2(0.f, 0.f);
        if (col < 200) v = *(const float2*)(b1 + col);
        *(float2*)&sh[B1O + 2 * tid] = v;
    }
    if (tid < 2) {                             // b0 (f2)
        const int col = c0b + 2 * tid;
        float2 v = make_float2(0.f, 0.f);
        if (col < 40) v = *(const float2*)(b0 + col);
        *(float2*)&sh[B0O + 2 * tid] = v;
    }
    __syncthreads();

    // ==== FOLD 1: cs into L4sh (per a,quad) + bias into biasf (per bin) ====
    // quads never straddle coarse-bin boundaries (20,40,200 all mult of 4).
#pragma unroll
    for (int k = 0; k < 5; k++) {
        const int u = tid + 256 * k;
        const int a = u >> 6, qd = u & 63;
        const int j = base + 4 * qd;
        const float v = sh[L4O + a * 64 + qd] + sh[L3O + a * 32 + (qd >> 1)]
                      + sh[L2O + a * 16 + (j / 20 - c2b)]
                      + sh[L1O + a * 8 + (j / 40 - c1b)]
                      + sh[L0O + a * 4 + (j / 200 - c0b)];
        sh[L4O + a * 64 + qd] = v;
    }
    {
        const int j = base + tid;
        const float add = sh[B5O + (tid >> 1)] + sh[B4O + (tid >> 2)]
                        + sh[B3O + (tid >> 3)] + sh[B2O + (j / 20 - c2b)]
                        + sh[B1O + (j / 40 - c1b)] + sh[B0O + (j / 200 - c0b)];
        sh[BFO + tid] += add;
    }
    __syncthreads();

    // ==== FOLD 2: U = L6 + L5 + cs, in place into L6sh ====
#pragma unroll
    for (int k = 0; k < 5; k++) {
        const int u = tid + 256 * k;
        const int a = u >> 6, q = u & 63;
        float4 v6 = *(float4*)&sh[L6O + a * 256 + 4 * q];
        const float2 v5 = *(const float2*)&sh[L5O + a * 128 + 2 * q];
        const float cs = sh[L4O + a * 64 + q];
        v6.x += v5.x + cs; v6.y += v5.x + cs;
        v6.z += v5.y + cs; v6.w += v5.y + cs;
        *(float4*)&sh[L6O + a * 256 + 4 * q] = v6;
    }
    __syncthreads();

    // ==== M1: KL syrk, fragments direct from global (L1/L2-hot) ====
    {
        f32x4 s00 = {0.f, 0.f, 0.f, 0.f};
        f32x4 s10 = {0.f, 0.f, 0.f, 0.f};
        f32x4 s11 = {0.f, 0.f, 0.f, 0.f};
#pragma unroll 1
        for (int ch = wv; ch < 15; ch += 4) {
            const float* P; int K, col0;
            if (ch < 8)       { P = p6; K = 8000; col0 = base + ch * 32; }
            else if (ch < 12) { P = p5; K = 4000; col0 = (base >> 1) + (ch - 8) * 32; }
            else if (ch < 14) { P = p4; K = 2000; col0 = (base >> 2) + (ch - 12) * 32; }
            else              { P = p3; K = 1000; col0 = (base >> 3); }
            const int cb = col0 + lg * 8;
            bf16x8 flo = {0,0,0,0,0,0,0,0}, fhi = {0,0,0,0,0,0,0,0};
            if (cb < K) {
                const float4 xa = *(const float4*)(P + (size_t)l15 * K + cb);
                const float4 xb = *(const float4*)(P + (size_t)l15 * K + cb + 4);
                flo = pack8(xa, xb);
                if (l15 < 4) {
                    const float4 ya = *(const float4*)(P + (size_t)(16 + l15) * K + cb);
                    const float4 yb = *(const float4*)(P + (size_t)(16 + l15) * K + cb + 4);
                    fhi = pack8(ya, yb);
                }
            }
            s00 = __builtin_amdgcn_mfma_f32_16x16x32_bf16(flo, flo, s00, 0, 0, 0);
            s10 = __builtin_amdgcn_mfma_f32_16x16x32_bf16(fhi, flo, s10, 0, 0, 0);
            s11 = __builtin_amdgcn_mfma_f32_16x16x32_bf16(fhi, fhi, s11, 0, 0, 0);
        }
        float qp = 0.f;
#pragma unroll
        for (int reg = 0; reg < 4; reg++) {
            const int rlo = lg * 4 + reg, rhi = 16 + lg * 4 + reg;
            qp += gfull[rlo * 32 + l15] * s00[reg];
            qp += 2.f * gfull[rhi * 32 + l15] * s10[reg];
            qp += gfull[rhi * 32 + 16 + l15] * s11[reg];
        }
#pragma unroll
        for (int off = 32; off > 0; off >>= 1) qp += __shfl_down(qp, off, 64);
        if (ln == 0) klp[wv] = qp;
    }

    // ==== M2: w = bias + comp^T U (r10-proven VALU path, SGPR comp) ====
    {
        const int cbase = __builtin_amdgcn_readfirstlane(wv * 5);
        const float* __restrict__ cc = compT + cbase * 20;   // uniform -> s_load
        const int j = base + 4 * ln;
        const bool ok = j < NFINAL;
        const float4 bi = *(const float4*)&sh[BFO + 4 * ln];
        {   // pass A: clusters cbase..cbase+2
            float4 a0 = bi, a1 = bi, a2 = bi;
#pragma unroll
            for (int a = 0; a < 20; a++) {
                const float4 u = *(const float4*)&sh[L6O + a * 256 + 4 * ln];
                const float f0 = cc[a], f1 = cc[20 + a], f2 = cc[40 + a];
                a0.x += f0 * u.x; a0.y += f0 * u.y; a0.z += f0 * u.z; a0.w += f0 * u.w;
                a1.x += f1 * u.x; a1.y += f1 * u.y; a1.z += f1 * u.z; a1.w += f1 * u.w;
                a2.x += f2 * u.x; a2.y += f2 * u.y; a2.z += f2 * u.z; a2.w += f2 * u.w;
            }
            float4 accs[3] = {a0, a1, a2};
#pragma unroll
            for (int k = 0; k < 3; k++) {
                float se = 0.f;
                if (ok) {
                    const float4 acc = accs[k];
                    union { __hip_bfloat162 h2[2]; uint2 u2; } pk;
                    pk.h2[0] = __float22bfloat162_rn(make_float2(acc.x, acc.y));
                    pk.h2[1] = __float22bfloat162_rn(make_float2(acc.z, acc.w));
                    *(uint2*)(w2 + (size_t)(r * 20 + cbase + k) * 8000 + j) = pk.u2;
                    // |w| small (~<4): unnormalized exp-sum safe in f32
                    se = __expf(acc.x) + __expf(acc.y) + __expf(acc.z) + __expf(acc.w);
                }
#pragma unroll
                for (int off = 32; off > 0; off >>= 1) se += __shfl_down(se, off, 64);
                if (ln == 0)
                    s_part[((size_t)r * NTILE + tile) * 20 + cbase + k] = se;
            }
        }
        {   // pass B: clusters cbase+3, cbase+4
            float4 a0 = bi, a1 = bi;
#pragma unroll
            for (int a = 0; a < 20; a++) {
                const float4 u = *(const float4*)&sh[L6O + a * 256 + 4 * ln];
                const float f0 = cc[60 + a], f1 = cc[80 + a];
                a0.x += f0 * u.x; a0.y += f0 * u.y; a0.z += f0 * u.z; a0.w += f0 * u.w;
                a1.x += f1 * u.x; a1.y += f1 * u.y; a1.z += f1 * u.z; a1.w += f1 * u.w;
            }
            float4 accs[2] = {a0, a1};
#pragma unroll
            for (int k = 0; k < 2; k++) {
                float se = 0.f;
                if (ok) {
                    const float4 acc = accs[k];
                    union { __hip_bfloat162 h2[2]; uint2 u2; } pk;
                    pk.h2[0] = __float22bfloat162_rn(make_float2(acc.x, acc.y));
                    pk.h2[1] = __float22bfloat162_rn(make_float2(acc.z, acc.w));
                    *(uint2*)(w2 + (size_t)(r * 20 + cbase + 3 + k) * 8000 + j) = pk.u2;
                    se = __expf(acc.x) + __expf(acc.y) + __expf(acc.z) + __expf(acc.w);
                }
#pragma unroll
                for (int off = 32; off > 0; off >>= 1) se += __shfl_down(se, off, 64);
                if (ln == 0)
                    s_part[((size_t)r * NTILE + tile) * 20 + cbase + 3 + k] = se;
            }
        }
    }
    __syncthreads();
    if (tid == 0) klbuf[blockIdx.x] = klp[0] + klp[1] + klp[2] + klp[3];
}

// KL quads for levels 0..2 (40+200+400 = 640 cols per region)
__global__ __launch_bounds__(256, 2) void k_klc(
    const float* __restrict__ g2,
    const float* __restrict__ wd0, const float* __restrict__ wd1,
    const float* __restrict__ wd2,
    const int* __restrict__ regions_oi, float* __restrict__ klbuf)
{
    __shared__ float klp[4];
    const int tid = threadIdx.x;
    const int r0 = regions_oi[blockIdx.x];
    const float* __restrict__ p2 = wd2 + (size_t)r0 * (20 * 400);
    const float* __restrict__ p1 = wd1 + (size_t)r0 * (20 * 200);
    const float* __restrict__ p0 = wd0 + (size_t)r0 * (20 * 40);

    float q = 0.f;
#pragma unroll 1
    for (int it = 0; it < 3; it++) {
        const int u = it * 256 + tid;
        if (u >= 640) break;
        const float* P; int K, col;
        if (u < 400)      { P = p2; K = 400; col = u; }
        else if (u < 600) { P = p1; K = 200; col = u - 400; }
        else              { P = p0; K = 40;  col = u - 600; }
        float x[20];
#pragma unroll
        for (int a = 0; a < 20; a++) x[a] = P[a * K + col];
#pragma unroll
        for (int a = 0; a < 20; a++) {
            float t = g2[a * 21] * x[a];
#pragma unroll
            for (int b = a + 1; b < 20; b++) t += g2[a * 20 + b] * x[b];
            q += x[a] * t;
        }
    }
#pragma unroll
    for (int off = 32; off > 0; off >>= 1) q += __shfl_down(q, off, 64);
    if ((tid & 63) == 0) klp[tid >> 6] = q;
    __syncthreads();
    if (tid == 0)
        klbuf[NROI * NTILE + blockIdx.x] = klp[0] + klp[1] + klp[2] + klp[3];
}

__global__ void k_klred(const float* __restrict__ klbuf, float* __restrict__ kl)
{
    __shared__ float part[4];
    const int tid = threadIdx.x;
    float s = 0.f;
    for (int i = tid; i < NKL; i += 256) s += klbuf[i];
#pragma unroll
    for (int off = 32; off > 0; off >>= 1) s += __shfl_down(s, off, 64);
    if ((tid & 63) == 0) part[tid >> 6] = s;
    __syncthreads();
    if (tid == 0)
        kl[0] = (float)(-80076800.0 * 1.3244036413128371)
              + (part[0] + part[1] + part[2] + part[3]) * (-0.5f / 2.25f);
}

__global__ void k_sub(const float* __restrict__ s_part, float* __restrict__ sub)
{
    const int i = blockIdx.x * 256 + threadIdx.x;
    if (i >= NROI * NC) return;
    const int r = i / 20, c = i % 20;
    float s = 0.f;
#pragma unroll 1
    for (int t = 0; t < NTILE; t++) s += s_part[(size_t)(r * NTILE + t) * 20 + c];
    sub[i] = logf(s) + 3.2188758248682006f;   // + log(25)
}

__global__ void k_gather(const int* __restrict__ lri, const int* __restrict__ lci,
                         const int* __restrict__ cli, const int* __restrict__ coords,
                         const __hip_bfloat16* __restrict__ w2,
                         const float* __restrict__ sub,
                         float* __restrict__ out)
{
    const int i = blockIdx.x * 256 + threadIdx.x;
    if (i >= NCUTS) return;
    const int r = lri[i];
    const int c = cli[lci[i]];
    int co = coords[i];
    co = co < 0 ? 0 : (co > 199999 ? 199999 : co);
    const int bin = co / 25;
    const int rc = r * 20 + c;
    out[i] = __bfloat162float(w2[(size_t)rc * 8000 + bin]) - sub[rc];
}

extern "C" void kernel_launch(void* const* d_in, const int* in_sizes, int n_in,
                              void* d_out, int out_size, void* d_ws, size_t ws_size,
                              hipStream_t stream)
{
    const float* comp = (const float*)d_in[0];
    const float* wb[7];
    const float* wd[7];
    if (in_sizes[2] == 400000) {
        for (int l = 0; l < 7; l++) { wb[l] = (const float*)d_in[1 + 2 * l]; wd[l] = (const float*)d_in[2 + 2 * l]; }
    } else {
        for (int l = 0; l < 7; l++) { wb[l] = (const float*)d_in[1 + l]; wd[l] = (const float*)d_in[8 + l]; }
    }
    const int* regions_oi = (const int*)d_in[15];
    const int* lri   = (const int*)d_in[16];
    const int* lci   = (const int*)d_in[17];
    const int* cli   = (const int*)d_in[18];
    const int* coords= (const int*)d_in[19];
    float* out = (float*)d_out;

    __hip_bfloat16* w2 = (__hip_bfloat16*)d_ws;                     // 81.92 MB
    float* s_part = (float*)(w2 + (size_t)NROI * NC * NFINAL);      // 8192*20
    float* sub    = s_part + (size_t)NROI * NTILE * 20;             // 5120
    float* g2buf  = sub + NROI * NC;                                // 400
    float* gfull  = g2buf + 400;                                    // 1024
    float* compT  = gfull + 1024;                                   // 400
    float* klbuf  = compT + 400;                                    // 8448
    const size_t need = (size_t)NROI * NC * NFINAL * 2
                      + ((size_t)NROI * NTILE * 20 + NROI * NC + 400 + 1024 + 400
                         + NKL) * sizeof(float);
    if (ws_size < need) return;

    k_init<<<1, 256, 0, stream>>>(comp, g2buf, gfull, compT);
    k_main<<<NROI * NTILE, 256, 0, stream>>>(gfull, compT,
        wb[0], wd[0], wb[1], wd[1], wb[2], wd[2], wb[3], wd[3],
        wb[4], wd[4], wb[5], wd[5], wb[6], wd[6],
        regions_oi, w2, s_part, klbuf);
    k_klc<<<NROI, 256, 0, stream>>>(g2buf, wd[0], wd[1], wd[2],
        regions_oi, klbuf);
    k_klred<<<1, 256, 0, stream>>>(klbuf, out + NCUTS);
    k_sub<<<(NROI * NC + 255) / 256, 256, 0, stream>>>(s_part, sub);
    k_gather<<<(NCUTS + 255) / 256, 256, 0, stream>>>(lri, lci, cli, coords,
        w2, sub, out);
}

// Round 18
// 202.908 us; speedup vs baseline: 2.6302x; 1.2807x over previous
//
#include <hip/hip_runtime.h>
#include <hip/hip_bf16.h>
#include <math.h>

// SharedLora on MI355X — round 18 = r15 with latency-restructured schedule.
// r16 decomposition (corrected): stage=65us (~roofline), M1+M2=131us of
// exposed post-barrier latency. r18: (a) M1 syrk moved BEFORE staging (it
// reads only global; loads merge with staging's load window, MFMA hides);
// (b) all phase loops fully unrolled (were #pragma unroll 1 serial chains);
// (c) everything else byte-identical to r15 (LDS 27KB, 5 blocks/CU, klbuf,
// no global atomics).

#define NROI 256
#define NC 20
#define NFINAL 8000
#define NCUTS 500000
#define TB 256
#define NTILE 32
#define UTSTR 40
#define NKL (NROI * NTILE + NROI)   // 8448 KL partial slots

typedef __attribute__((ext_vector_type(8))) short bf16x8;
typedef __attribute__((ext_vector_type(4))) float f32x4;

static __device__ __forceinline__ ushort bfr(float x) {
    union { __hip_bfloat16 h; ushort u; } v;
    v.h = __float2bfloat16(x);
    return v.u;
}
static __device__ __forceinline__ bf16x8 pack8(float4 a, float4 b) {
    union { bf16x8 v; ushort s[8]; } u;
    u.s[0] = bfr(a.x); u.s[1] = bfr(a.y); u.s[2] = bfr(a.z); u.s[3] = bfr(a.w);
    u.s[4] = bfr(b.x); u.s[5] = bfr(b.y); u.s[6] = bfr(b.z); u.s[7] = bfr(b.w);
    return u.v;
}

__global__ void k_init(const float* __restrict__ comp,
                       float* __restrict__ g2, float* __restrict__ gfull,
                       ushort* __restrict__ compPad)
{
    const int tid = threadIdx.x;
    for (int i = tid; i < 400; i += 256) {
        const int a = i / 20, b = i % 20;
        float s = 0.f;
#pragma unroll
        for (int c = 0; c < 20; c++) s += comp[a * 20 + c] * comp[b * 20 + c];
        g2[i] = (b < a) ? 0.f : (b == a ? s : 2.f * s);
    }
    for (int i = tid; i < 1024; i += 256) {
        const int rr = i >> 5, cc = i & 31;
        float s = 0.f;
        if (rr < 20 && cc < 20) {
#pragma unroll
            for (int c = 0; c < 20; c++) s += comp[rr * 20 + c] * comp[cc * 20 + c];
        }
        gfull[i] = s;
        const float v = (rr < 20 && cc < 20) ? comp[cc * 20 + rr] : 0.f;
        compPad[i] = bfr(v);
    }
}

__global__ __launch_bounds__(256, 2) void k_main(
    const float* __restrict__ gfull, const ushort* __restrict__ compPad,
    const float* __restrict__ wb0, const float* __restrict__ wd0,
    const float* __restrict__ wb1, const float* __restrict__ wd1,
    const float* __restrict__ wb2, const float* __restrict__ wd2,
    const float* __restrict__ wb3, const float* __restrict__ wd3,
    const float* __restrict__ wb4, const float* __restrict__ wd4,
    const float* __restrict__ wb5, const float* __restrict__ wd5,
    const float* __restrict__ wb6, const float* __restrict__ wd6,
    const int* __restrict__ regions_oi,
    __hip_bfloat16* __restrict__ w2,
    float* __restrict__ s_part, float* __restrict__ klbuf)
{
    __shared__ ushort Utsh[TB * UTSTR];   // 20,480 B
    __shared__ float cs_sh[20 * 64];      // 5,120 B
    __shared__ float biasf[TB];           // 1,024 B
    __shared__ float sexp_sh[20];
    __shared__ float klp[4];

    const int tid = threadIdx.x;
    const int wv = tid >> 6, ln = tid & 63;
    const int l15 = ln & 15, lg = ln >> 4;
    const int r = blockIdx.x >> 5;
    const int tile = blockIdx.x & 31;
    const int base = tile << 8;
    const int r0 = regions_oi[r];

    const float* __restrict__ p6 = wd6 + (size_t)r0 * (20 * 8000);
    const float* __restrict__ p5 = wd5 + (size_t)r0 * (20 * 4000);
    const float* __restrict__ p4 = wd4 + (size_t)r0 * (20 * 2000);
    const float* __restrict__ p3 = wd3 + (size_t)r0 * (20 * 1000);
    const float* __restrict__ p2 = wd2 + (size_t)r0 * (20 * 400);
    const float* __restrict__ p1 = wd1 + (size_t)r0 * (20 * 200);
    const float* __restrict__ p0 = wd0 + (size_t)r0 * (20 * 40);
    const float* __restrict__ b6 = wb6 + (size_t)r0 * 8000;
    const float* __restrict__ b5 = wb5 + (size_t)r0 * 4000;
    const float* __restrict__ b4 = wb4 + (size_t)r0 * 2000;
    const float* __restrict__ b3 = wb3 + (size_t)r0 * 1000;
    const float* __restrict__ b2 = wb2 + (size_t)r0 * 400;
    const float* __restrict__ b1 = wb1 + (size_t)r0 * 200;
    const float* __restrict__ b0 = wb0 + (size_t)r0 * 40;

    if (tid < 20) sexp_sh[tid] = 0.f;

    // ==== M1 FIRST: KL syrk on global data (overlaps with staging below) ====
    {
        f32x4 s00 = {0.f, 0.f, 0.f, 0.f};
        f32x4 s10 = {0.f, 0.f, 0.f, 0.f};
        f32x4 s11 = {0.f, 0.f, 0.f, 0.f};
#pragma unroll
        for (int i = 0; i < 4; i++) {
            const int ch = wv + 4 * i;
            if (ch < 15) {
                const float* P; int K, col0;
                if (ch < 8)       { P = p6; K = 8000; col0 = base + ch * 32; }
                else if (ch < 12) { P = p5; K = 4000; col0 = (base >> 1) + (ch - 8) * 32; }
                else if (ch < 14) { P = p4; K = 2000; col0 = (base >> 2) + (ch - 12) * 32; }
                else              { P = p3; K = 1000; col0 = (base >> 3); }
                const int cb = col0 + lg * 8;
                bf16x8 flo = {0,0,0,0,0,0,0,0}, fhi = {0,0,0,0,0,0,0,0};
                if (cb < K) {
                    const float4 xa = *(const float4*)(P + (size_t)l15 * K + cb);
                    const float4 xb = *(const float4*)(P + (size_t)l15 * K + cb + 4);
                    flo = pack8(xa, xb);
                    if (l15 < 4) {
                        const float4 ya = *(const float4*)(P + (size_t)(16 + l15) * K + cb);
                        const float4 yb = *(const float4*)(P + (size_t)(16 + l15) * K + cb + 4);
                        fhi = pack8(ya, yb);
                    }
                }
                s00 = __builtin_amdgcn_mfma_f32_16x16x32_bf16(flo, flo, s00, 0, 0, 0);
                s10 = __builtin_amdgcn_mfma_f32_16x16x32_bf16(fhi, flo, s10, 0, 0, 0);
                s11 = __builtin_amdgcn_mfma_f32_16x16x32_bf16(fhi, fhi, s11, 0, 0, 0);
            }
        }
        float qp = 0.f;
#pragma unroll
        for (int reg = 0; reg < 4; reg++) {
            const int rlo = lg * 4 + reg, rhi = 16 + lg * 4 + reg;
            qp += gfull[rlo * 32 + l15] * s00[reg];
            qp += 2.f * gfull[rhi * 32 + l15] * s10[reg];
            qp += gfull[rhi * 32 + 16 + l15] * s11[reg];
        }
#pragma unroll
        for (int off = 32; off > 0; off >>= 1) qp += __shfl_down(qp, off, 64);
        if (ln == 0) klp[wv] = qp;
    }

    // ==== C: coarse sums cs[a][quad] + bias per bin (fully unrolled) ====
#pragma unroll
    for (int it = 0; it < 5; it++) {
        const int u = it * 256 + tid;
        const int a = u >> 6, qd = u & 63;
        const int j = base + 4 * qd;
        float v = 0.f;
        if (j < NFINAL)
            v = p4[a * 2000 + (j >> 2)] + p3[a * 1000 + (j >> 3)]
              + p2[a * 400 + j / 20] + p1[a * 200 + j / 40]
              + p0[a * 40 + j / 200];
        cs_sh[a * 64 + qd] = v;
    }
    {
        const int j = base + tid;
        float v = 0.f;
        if (j < NFINAL)
            v = b6[j] + b5[j >> 1] + b4[j >> 2] + b3[j >> 3]
              + b2[j / 20] + b1[j / 40] + b0[j / 200];
        biasf[tid] = v;
    }
    __syncthreads();

    // ==== U: Utsh[bin][a] bf16 (pads 20..31 zero), fully unrolled ====
    {
        const int j = base + tid;
        const bool ok = j < NFINAL;
        const int qd = tid >> 2;
#pragma unroll
        for (int it = 0; it < 5; it++) {
            float u[4];
#pragma unroll
            for (int i = 0; i < 4; i++) {
                const int a = 4 * it + i;
                float x6 = 0.f, x5 = 0.f;
                if (ok) {
                    x6 = p6[(size_t)a * 8000 + j];
                    x5 = p5[a * 4000 + (j >> 1)];
                }
                u[i] = x6 + x5 + cs_sh[a * 64 + qd];
            }
            *(ushort4*)&Utsh[tid * UTSTR + 4 * it] =
                make_ushort4(bfr(u[0]), bfr(u[1]), bfr(u[2]), bfr(u[3]));
        }
        const ushort4 z4 = make_ushort4(0, 0, 0, 0);
        *(ushort4*)&Utsh[tid * UTSTR + 20] = z4;
        *(ushort4*)&Utsh[tid * UTSTR + 24] = z4;
        *(ushort4*)&Utsh[tid * UTSTR + 28] = z4;
    }
    __syncthreads();

    // ==== M2: w = bias + comp^T U via MFMA (fully unrolled) ====
    {
        bf16x8 fA0 = *(const bf16x8*)&compPad[l15 * 32 + lg * 8];
        bf16x8 fA1 = *(const bf16x8*)&compPad[(16 + l15) * 32 + lg * 8];
        float sA[4] = {0.f, 0.f, 0.f, 0.f};
        float sB[4] = {0.f, 0.f, 0.f, 0.f};
#pragma unroll
        for (int t = 0; t < 4; t++) {
            const int nt = 4 * t + wv;
            bf16x8 fB = *(const bf16x8*)&Utsh[(nt * 16 + l15) * UTSTR + lg * 8];
            const f32x4 z = {0.f, 0.f, 0.f, 0.f};
            f32x4 c0 = __builtin_amdgcn_mfma_f32_16x16x32_bf16(fA0, fB, z, 0, 0, 0);
            f32x4 c1 = __builtin_amdgcn_mfma_f32_16x16x32_bf16(fA1, fB, z, 0, 0, 0);
            const int binl = nt * 16 + l15;
            const int bin = base + binl;
            const float bi = biasf[binl];
            if (bin < NFINAL) {
#pragma unroll
                for (int reg = 0; reg < 4; reg++) {
                    const int c = lg * 4 + reg;
                    const float w = bi + c0[reg];
                    w2[(size_t)(r * 20 + c) * 8000 + bin] = __float2bfloat16(w);
                    sA[reg] += __expf(w);                   // |w|<~4: safe f32
                }
                if (lg == 0) {
#pragma unroll
                    for (int reg = 0; reg < 4; reg++) {
                        const float w = bi + c1[reg];
                        w2[(size_t)(r * 20 + 16 + reg) * 8000 + bin] = __float2bfloat16(w);
                        sB[reg] += __expf(w);
                    }
                }
            }
        }
#pragma unroll
        for (int reg = 0; reg < 4; reg++) {
            float s = sA[reg];
            s += __shfl_xor(s, 1, 64); s += __shfl_xor(s, 2, 64);
            s += __shfl_xor(s, 4, 64); s += __shfl_xor(s, 8, 64);
            if (l15 == 0) atomicAdd(&sexp_sh[lg * 4 + reg], s);
            float sb = sB[reg];
            sb += __shfl_xor(sb, 1, 64); sb += __shfl_xor(sb, 2, 64);
            sb += __shfl_xor(sb, 4, 64); sb += __shfl_xor(sb, 8, 64);
            if (ln == 0) atomicAdd(&sexp_sh[16 + reg], sb);
        }
    }
    __syncthreads();
    if (tid < 20) s_part[((size_t)r * NTILE + tile) * 20 + tid] = sexp_sh[tid];
    if (tid == 0) klbuf[blockIdx.x] = klp[0] + klp[1] + klp[2] + klp[3];
}

// KL quads for levels 0..2 (40+200+400 = 640 cols per region)
__global__ __launch_bounds__(256, 2) void k_klc(
    const float* __restrict__ g2,
    const float* __restrict__ wd0, const float* __restrict__ wd1,
    const float* __restrict__ wd2,
    const int* __restrict__ regions_oi, float* __restrict__ klbuf)
{
    __shared__ float klp[4];
    const int tid = threadIdx.x;
    const int r0 = regions_oi[blockIdx.x];
    const float* __restrict__ p2 = wd2 + (size_t)r0 * (20 * 400);
    const float* __restrict__ p1 = wd1 + (size_t)r0 * (20 * 200);
    const float* __restrict__ p0 = wd0 + (size_t)r0 * (20 * 40);

    float q = 0.f;
#pragma unroll 1
    for (int it = 0; it < 3; it++) {
        const int u = it * 256 + tid;
        if (u >= 640) break;
        const float* P; int K, col;
        if (u < 400)      { P = p2; K = 400; col = u; }
        else if (u < 600) { P = p1; K = 200; col = u - 400; }
        else              { P = p0; K = 40;  col = u - 600; }
        float x[20];
#pragma unroll
        for (int a = 0; a < 20; a++) x[a] = P[a * K + col];
#pragma unroll
        for (int a = 0; a < 20; a++) {
            float t = g2[a * 21] * x[a];
#pragma unroll
            for (int b = a + 1; b < 20; b++) t += g2[a * 20 + b] * x[b];
            q += x[a] * t;
        }
    }
#pragma unroll
    for (int off = 32; off > 0; off >>= 1) q += __shfl_down(q, off, 64);
    if ((tid & 63) == 0) klp[tid >> 6] = q;
    __syncthreads();
    if (tid == 0)
        klbuf[NROI * NTILE + blockIdx.x] = klp[0] + klp[1] + klp[2] + klp[3];
}

__global__ void k_klred(const float* __restrict__ klbuf, float* __restrict__ kl)
{
    __shared__ float part[4];
    const int tid = threadIdx.x;
    float s = 0.f;
    for (int i = tid; i < NKL; i += 256) s += klbuf[i];
#pragma unroll
    for (int off = 32; off > 0; off >>= 1) s += __shfl_down(s, off, 64);
    if ((tid & 63) == 0) part[tid >> 6] = s;
    __syncthreads();
    if (tid == 0)
        kl[0] = (float)(-80076800.0 * 1.3244036413128371)
              + (part[0] + part[1] + part[2] + part[3]) * (-0.5f / 2.25f);
}

__global__ void k_sub(const float* __restrict__ s_part, float* __restrict__ sub)
{
    const int i = blockIdx.x * 256 + threadIdx.x;
    if (i >= NROI * NC) return;
    const int r = i / 20, c = i % 20;
    float s = 0.f;
#pragma unroll 1
    for (int t = 0; t < NTILE; t++) s += s_part[(size_t)(r * NTILE + t) * 20 + c];
    sub[i] = logf(s) + 3.2188758248682006f;   // + log(25)
}

__global__ void k_gather(const int* __restrict__ lri, const int* __restrict__ lci,
                         const int* __restrict__ cli, const int* __restrict__ coords,
                         const __hip_bfloat16* __restrict__ w2,
                         const float* __restrict__ sub,
                         float* __restrict__ out)
{
    const int i = blockIdx.x * 256 + threadIdx.x;
    if (i >= NCUTS) return;
    const int r = lri[i];
    const int c = cli[lci[i]];
    int co = coords[i];
    co = co < 0 ? 0 : (co > 199999 ? 199999 : co);
    const int bin = co / 25;
    const int rc = r * 20 + c;
    out[i] = __bfloat162float(w2[(size_t)rc * 8000 + bin]) - sub[rc];
}

extern "C" void kernel_launch(void* const* d_in, const int* in_sizes, int n_in,
                              void* d_out, int out_size, void* d_ws, size_t ws_size,
                              hipStream_t stream)
{
    const float* comp = (const float*)d_in[0];
    const float* wb[7];
    const float* wd[7];
    if (in_sizes[2] == 400000) {
        for (int l = 0; l < 7; l++) { wb[l] = (const float*)d_in[1 + 2 * l]; wd[l] = (const float*)d_in[2 + 2 * l]; }
    } else {
        for (int l = 0; l < 7; l++) { wb[l] = (const float*)d_in[1 + l]; wd[l] = (const float*)d_in[8 + l]; }
    }
    const int* regions_oi = (const int*)d_in[15];
    const int* lri   = (const int*)d_in[16];
    const int* lci   = (const int*)d_in[17];
    const int* cli   = (const int*)d_in[18];
    const int* coords= (const int*)d_in[19];
    float* out = (float*)d_out;

    __hip_bfloat16* w2 = (__hip_bfloat16*)d_ws;                     // 81.92 MB
    float* s_part = (float*)(w2 + (size_t)NROI * NC * NFINAL);      // 8192*20
    float* sub    = s_part + (size_t)NROI * NTILE * 20;             // 5120
    float* g2buf  = sub + NROI * NC;                                // 400
    float* gfull  = g2buf + 400;                                    // 1024
    ushort* compPad = (ushort*)(gfull + 1024);                      // 1024 u16
    float* klbuf  = (float*)(compPad + 1024);                       // 8448
    const size_t need = (size_t)NROI * NC * NFINAL * 2
                      + ((size_t)NROI * NTILE * 20 + NROI * NC + 400 + 1024 + 512
                         + NKL) * sizeof(float);
    if (ws_size < need) return;

    k_init<<<1, 256, 0, stream>>>(comp, g2buf, gfull, compPad);
    k_main<<<NROI * NTILE, 256, 0, stream>>>(gfull, compPad,
        wb[0], wd[0], wb[1], wd[1], wb[2], wd[2], wb[3], wd[3],
        wb[4], wd[4], wb[5], wd[5], wb[6], wd[6],
        regions_oi, w2, s_part, klbuf);
    k_klc<<<NROI, 256, 0, stream>>>(g2buf, wd[0], wd[1], wd[2],
        regions_oi, klbuf);
    k_klred<<<1, 256, 0, stream>>>(klbuf, out + NCUTS);
    k_sub<<<(NROI * NC + 255) / 256, 256, 0, stream>>>(s_part, sub);
    k_gather<<<(NCUTS + 255) / 256, 256, 0, stream>>>(lri, lci, cli, coords,
        w2, sub, out);
}